// Round 2
// baseline (1122.941 us; speedup 1.0000x reference)
//
#include <hip/hip_runtime.h>
#include <stdint.h>

#define N_NODES 50000
#define N_EDGES 800000
#define FEAT    128
#define NGRAPH  64

typedef __attribute__((ext_vector_type(8))) short short8;
typedef __attribute__((ext_vector_type(4))) float floatx4;

static __device__ __forceinline__ ushort f2bf(float f) {
  uint32_t x = __float_as_uint(f);
  x += 0x7FFF + ((x >> 16) & 1);   // RNE
  return (ushort)(x >> 16);
}

// ---------------- fp32 -> bf16 conversion (x and conv weights) -----------
__global__ __launch_bounds__(256) void cvt_bf16(const float* __restrict__ in,
                                                ushort* __restrict__ out, int n4) {
  int i = blockIdx.x * 256 + threadIdx.x;
  if (i >= n4) return;
  float4 v = ((const float4*)in)[i];
  ushort4 u;
  u.x = f2bf(v.x); u.y = f2bf(v.y); u.z = f2bf(v.z); u.w = f2bf(v.w);
  ((ushort4*)out)[i] = u;
}

// ---------------- degree count -------------------------------------------
__global__ __launch_bounds__(256) void count_deg(const int* __restrict__ dst,
                                                 int* __restrict__ cnt) {
  int e = blockIdx.x * 256 + threadIdx.x;
  if (e < N_EDGES) atomicAdd(&cnt[dst[e]], 1);
}

// ---------------- dinv = rsqrt(deg+1) ------------------------------------
__global__ __launch_bounds__(256) void compute_dinv(const int* __restrict__ cnt,
                                                    float* __restrict__ dinv) {
  int i = blockIdx.x * 256 + threadIdx.x;
  if (i < N_NODES) dinv[i] = rsqrtf((float)cnt[i] + 1.0f);
}

// ---------------- exclusive scan (3 kernels) -----------------------------
__global__ __launch_bounds__(256) void scan1(const int* __restrict__ cnt,
                                             int* __restrict__ ptr,
                                             int* __restrict__ bsums) {
  __shared__ int tmp[256];
  int i = blockIdx.x * 256 + threadIdx.x;
  int v = (i < N_NODES) ? cnt[i] : 0;
  tmp[threadIdx.x] = v;
  __syncthreads();
  for (int off = 1; off < 256; off <<= 1) {
    int t = (threadIdx.x >= off) ? tmp[threadIdx.x - off] : 0;
    __syncthreads();
    tmp[threadIdx.x] += t;
    __syncthreads();
  }
  if (i < N_NODES) ptr[i] = tmp[threadIdx.x] - v;           // exclusive
  if (threadIdx.x == 255) bsums[blockIdx.x] = tmp[255];
}

__global__ __launch_bounds__(256) void scan2(int* __restrict__ bsums, int nb) {
  __shared__ int tmp[256];
  int v = (threadIdx.x < nb) ? bsums[threadIdx.x] : 0;
  tmp[threadIdx.x] = v;
  __syncthreads();
  for (int off = 1; off < 256; off <<= 1) {
    int t = (threadIdx.x >= off) ? tmp[threadIdx.x - off] : 0;
    __syncthreads();
    tmp[threadIdx.x] += t;
    __syncthreads();
  }
  if (threadIdx.x < nb) bsums[threadIdx.x] = tmp[threadIdx.x] - v;  // exclusive
}

__global__ __launch_bounds__(256) void scan3(int* __restrict__ ptr,
                                             int* __restrict__ cursor,
                                             const int* __restrict__ bsums) {
  int i = blockIdx.x * 256 + threadIdx.x;
  if (i < N_NODES) {
    int p = ptr[i] + bsums[blockIdx.x];
    ptr[i] = p;
    cursor[i] = p;
  }
}

// ---------------- CSR fill (src + fused norm) ----------------------------
__global__ __launch_bounds__(256) void fill_csr(const int* __restrict__ src,
                                                const int* __restrict__ dst,
                                                const float* __restrict__ dinv,
                                                int* __restrict__ cursor,
                                                int2* __restrict__ edges) {
  int e = blockIdx.x * 256 + threadIdx.x;
  if (e >= N_EDGES) return;
  int s = src[e], d = dst[e];
  int pos = atomicAdd(&cursor[d], 1);
  float nrm = dinv[s] * dinv[d];
  edges[pos] = make_int2(s, __float_as_int(nrm));
}

// ---------------- GEMM [M,128] x [128,128] via MFMA bf16 -----------------
// A: bf16 row-major [M][128]; W: bf16 row-major [128][128] (k-major rows).
// One wave = 16x16 output tile; K=128 via 4x mfma_f32_16x16x32_bf16.
__global__ __launch_bounds__(256) void gemm128(const ushort* __restrict__ X,
                                               const ushort* __restrict__ W,
                                               float* __restrict__ XW,
                                               int nTilesM) {
  int wave = (blockIdx.x * 256 + threadIdx.x) >> 6;
  int lane = threadIdx.x & 63;
  int mt = wave >> 3;  // 8 n-tiles per m-tile
  int nt = wave & 7;
  if (mt >= nTilesM) return;
  int m0 = mt * 16, n0 = nt * 16;
  int r = lane & 15, quad = lane >> 4;
  floatx4 acc = {0.f, 0.f, 0.f, 0.f};
  const ushort* xrow = X + (size_t)(m0 + r) * FEAT;
#pragma unroll
  for (int kb = 0; kb < 4; ++kb) {
    int k0 = kb * 32 + quad * 8;
    short8 a = *(const short8*)(xrow + k0);
    short8 b;
#pragma unroll
    for (int j = 0; j < 8; ++j) b[j] = (short)W[(size_t)(k0 + j) * FEAT + n0 + r];
    acc = __builtin_amdgcn_mfma_f32_16x16x32_bf16(a, b, acc, 0, 0, 0);
  }
#pragma unroll
  for (int reg = 0; reg < 4; ++reg) {
    int row = quad * 4 + reg;
    XW[(size_t)(m0 + row) * FEAT + n0 + r] = acc[reg];
  }
}

// ---------------- aggregation: one wave per node -------------------------
// mode 0: h = relu(agg + b) -> bf16 Hout (next GEMM's A operand)
// mode 1: v = agg + b; atomicAdd into f_sum[batch[node]*128 + feat]
__global__ __launch_bounds__(256) void agg_kernel(const float* __restrict__ XW,
                                                  const float* __restrict__ dinv,
                                                  const int* __restrict__ ptr,
                                                  const int* __restrict__ cnt,
                                                  const int2* __restrict__ edges,
                                                  const float* __restrict__ bias,
                                                  ushort* __restrict__ Hout,
                                                  float* __restrict__ f_sum,
                                                  const int* __restrict__ batch,
                                                  int mode) {
  int wave = (blockIdx.x * 256 + threadIdx.x) >> 6;
  int lane = threadIdx.x & 63;
  if (wave >= N_NODES) return;
  int v = wave;
  float di = dinv[v];
  const float2* xw2 = (const float2*)XW;   // 64 float2 per node row
  float2 self = xw2[(size_t)v * 64 + lane];
  float sn = di * di;
  float ax = self.x * sn, ay = self.y * sn;
  int start = ptr[v];
  int n = cnt[v];
  for (int i = 0; i < n; ++i) {
    int2 e = edges[start + i];
    float nrm = __int_as_float(e.y);
    float2 m = xw2[(size_t)e.x * 64 + lane];
    ax = fmaf(nrm, m.x, ax);
    ay = fmaf(nrm, m.y, ay);
  }
  ax += bias[2 * lane];
  ay += bias[2 * lane + 1];
  if (mode == 0) {
    ax = fmaxf(ax, 0.f);
    ay = fmaxf(ay, 0.f);
    ushort2 h2;
    h2.x = f2bf(ax);
    h2.y = f2bf(ay);
    ((ushort2*)Hout)[(size_t)v * 64 + lane] = h2;
  } else {
    int g = batch[v];
    atomicAdd(&f_sum[g * FEAT + 2 * lane], ax);
    atomicAdd(&f_sum[g * FEAT + 2 * lane + 1], ay);
  }
}

// ---------------- per-graph node counts (LDS binned) ---------------------
__global__ __launch_bounds__(256) void count_graphs(const int* __restrict__ batch,
                                                    float* __restrict__ cnt_g) {
  __shared__ int bins[NGRAPH];
  if (threadIdx.x < NGRAPH) bins[threadIdx.x] = 0;
  __syncthreads();
  int i = blockIdx.x * 256 + threadIdx.x;
  if (i < N_NODES) atomicAdd(&bins[batch[i]], 1);
  __syncthreads();
  if (threadIdx.x < NGRAPH && bins[threadIdx.x] > 0)
    atomicAdd(&cnt_g[threadIdx.x], (float)bins[threadIdx.x]);
}

// ---------------- finalize f = sums / cnt (fp32 out, is output 0) --------
__global__ __launch_bounds__(256) void finalize_f(const float* __restrict__ f_sum,
                                                  const float* __restrict__ cnt_g,
                                                  float* __restrict__ out_f) {
  int i = blockIdx.x * 256 + threadIdx.x;
  if (i < NGRAPH * FEAT) {
    float c = fmaxf(cnt_g[i >> 7], 1.0f);
    out_f[i] = f_sum[i] / c;
  }
}

// ---------------- small FC layer: out[r][c] = act(in[r]·w[:,c] + b[c]) ---
__global__ __launch_bounds__(256) void fc_layer(const float* __restrict__ in,
                                                const float* __restrict__ w,
                                                const float* __restrict__ b,
                                                float* __restrict__ out,
                                                int K, int C, int relu) {
  int idx = blockIdx.x * 256 + threadIdx.x;
  if (idx >= NGRAPH * C) return;
  int r = idx / C, c = idx - r * C;
  const float* inr = in + (size_t)r * K;
  float acc = b[c];
  for (int k = 0; k < K; ++k) acc = fmaf(inr[k], w[(size_t)k * C + c], acc);
  if (relu) acc = fmaxf(acc, 0.f);
  out[idx] = acc;
}

// =========================================================================
extern "C" void kernel_launch(void* const* d_in, const int* in_sizes, int n_in,
                              void* d_out, int out_size, void* d_ws, size_t ws_size,
                              hipStream_t stream) {
  // inputs (setup_inputs order) — all floats are fp32, ints are int32
  const float* x         = (const float*)d_in[0];
  const int*   ei        = (const int*)d_in[1];     // [2][E]: row0 src, row1 dst
  const int*   batch     = (const int*)d_in[2];
  const float* conv_w[3] = {(const float*)d_in[3], (const float*)d_in[5], (const float*)d_in[7]};
  const float* conv_b[3] = {(const float*)d_in[4], (const float*)d_in[6], (const float*)d_in[8]};
  const float* fc_w[5]   = {(const float*)d_in[9],  (const float*)d_in[11],
                            (const float*)d_in[13], (const float*)d_in[15],
                            (const float*)d_in[17]};
  const float* fc_b[5]   = {(const float*)d_in[10], (const float*)d_in[12],
                            (const float*)d_in[14], (const float*)d_in[16],
                            (const float*)d_in[18]};
  const int* e_src = ei;
  const int* e_dst = ei + N_EDGES;
  float* out_f = (float*)d_out;                  // [64][128] fp32  (output 0)
  float* out_y = (float*)d_out + NGRAPH * FEAT;  // [64][10]  fp32  (output 1)

  // workspace carve-up (256B aligned)
  char* p = (char*)d_ws;
  auto carve = [&](size_t bytes) {
    char* r = p;
    p += (bytes + 255) & ~(size_t)255;
    return r;
  };
  int*    cnt_i   = (int*)carve(N_NODES * 4);
  float*  dinv    = (float*)carve(N_NODES * 4);
  int*    csr_ptr = (int*)carve(N_NODES * 4);
  int*    cursor  = (int*)carve(N_NODES * 4);
  int*    bsums   = (int*)carve(256 * 4);
  int2*   edges   = (int2*)carve((size_t)N_EDGES * 8);
  ushort* xb      = (ushort*)carve((size_t)N_NODES * FEAT * 2);   // bf16 x
  ushort* wb      = (ushort*)carve((size_t)3 * FEAT * FEAT * 2);  // bf16 conv weights
  float*  xw      = (float*)carve((size_t)N_NODES * FEAT * 4);
  ushort* hbuf    = (ushort*)carve((size_t)N_NODES * FEAT * 2);
  float*  f_sum   = (float*)carve(NGRAPH * FEAT * 4);
  float*  cnt_g   = (float*)carve(NGRAPH * 4);
  float*  act1    = (float*)carve(NGRAPH * 1024 * 4);
  float*  act2    = (float*)carve(NGRAPH * 512 * 4);

  const int BLK_E = (N_EDGES + 255) / 256;   // 3125
  const int BLK_N = (N_NODES + 255) / 256;   // 196

  // zero what must start at zero (ws is poisoned 0xAA each timed call)
  hipMemsetAsync(cnt_i, 0, N_NODES * 4, stream);
  hipMemsetAsync(f_sum, 0, NGRAPH * FEAT * 4, stream);
  hipMemsetAsync(cnt_g, 0, NGRAPH * 4, stream);

  // ---- fp32 -> bf16 prep (x, conv weights) ----
  cvt_bf16<<<(N_NODES * FEAT / 4 + 255) / 256, 256, 0, stream>>>(x, xb, N_NODES * FEAT / 4);
  cvt_bf16<<<(FEAT * FEAT / 4 + 255) / 256, 256, 0, stream>>>(conv_w[0], wb,                 FEAT * FEAT / 4);
  cvt_bf16<<<(FEAT * FEAT / 4 + 255) / 256, 256, 0, stream>>>(conv_w[1], wb + FEAT * FEAT,   FEAT * FEAT / 4);
  cvt_bf16<<<(FEAT * FEAT / 4 + 255) / 256, 256, 0, stream>>>(conv_w[2], wb + 2 * FEAT * FEAT, FEAT * FEAT / 4);

  // ---- build CSR + norms (once; reused by all 3 convs) ----
  count_deg<<<BLK_E, 256, 0, stream>>>(e_dst, cnt_i);
  compute_dinv<<<BLK_N, 256, 0, stream>>>(cnt_i, dinv);
  scan1<<<BLK_N, 256, 0, stream>>>(cnt_i, csr_ptr, bsums);
  scan2<<<1, 256, 0, stream>>>(bsums, BLK_N);
  scan3<<<BLK_N, 256, 0, stream>>>(csr_ptr, cursor, bsums);
  fill_csr<<<BLK_E, 256, 0, stream>>>(e_src, e_dst, dinv, cursor, edges);

  const int GEMM_BLKS = (N_NODES / 16) * 8 / 4;  // 3125 m-tiles * 8 n-tiles / 4 waves
  const int AGG_BLKS  = (N_NODES + 3) / 4;       // 1 wave/node, 4 waves/block

  // ---- conv1 ----
  gemm128<<<GEMM_BLKS, 256, 0, stream>>>(xb, wb, xw, N_NODES / 16);
  agg_kernel<<<AGG_BLKS, 256, 0, stream>>>(xw, dinv, csr_ptr, cnt_i, edges,
                                           conv_b[0], hbuf, f_sum, batch, 0);
  // ---- conv2 ----
  gemm128<<<GEMM_BLKS, 256, 0, stream>>>(hbuf, wb + FEAT * FEAT, xw, N_NODES / 16);
  agg_kernel<<<AGG_BLKS, 256, 0, stream>>>(xw, dinv, csr_ptr, cnt_i, edges,
                                           conv_b[1], hbuf, f_sum, batch, 0);
  // ---- conv3 + fused mean-pool numerator ----
  gemm128<<<GEMM_BLKS, 256, 0, stream>>>(hbuf, wb + 2 * FEAT * FEAT, xw, N_NODES / 16);
  agg_kernel<<<AGG_BLKS, 256, 0, stream>>>(xw, dinv, csr_ptr, cnt_i, edges,
                                           conv_b[2], hbuf, f_sum, batch, 1);

  // ---- pool ----
  count_graphs<<<BLK_N, 256, 0, stream>>>(batch, cnt_g);
  finalize_f<<<(NGRAPH * FEAT + 255) / 256, 256, 0, stream>>>(f_sum, cnt_g, out_f);

  // ---- FC head (pure fp32) ----
  fc_layer<<<(NGRAPH * 1024 + 255) / 256, 256, 0, stream>>>(out_f, fc_w[0], fc_b[0], act1, 128, 1024, 1);
  fc_layer<<<(NGRAPH * 512 + 255) / 256, 256, 0, stream>>>(act1, fc_w[1], fc_b[1], act2, 1024, 512, 1);
  fc_layer<<<(NGRAPH * 256 + 255) / 256, 256, 0, stream>>>(act2, fc_w[2], fc_b[2], act1, 512, 256, 1);
  fc_layer<<<(NGRAPH * 128 + 255) / 256, 256, 0, stream>>>(act1, fc_w[3], fc_b[3], act2, 256, 128, 1);
  fc_layer<<<(NGRAPH * 10 + 255) / 256, 256, 0, stream>>>(act2, fc_w[4], fc_b[4], out_y, 128, 10, 0);
}

// Round 3
// 701.666 us; speedup vs baseline: 1.6004x; 1.6004x over previous
//
#include <hip/hip_runtime.h>
#include <stdint.h>

#define N_NODES 50000
#define N_EDGES 800000
#define FEAT    128
#define NGRAPH  64

typedef __attribute__((ext_vector_type(8))) short short8;
typedef __attribute__((ext_vector_type(4))) float floatx4;

static __device__ __forceinline__ ushort f2bf(float f) {
  uint32_t x = __float_as_uint(f);
  x += 0x7FFF + ((x >> 16) & 1);   // RNE
  return (ushort)(x >> 16);
}

// ---------------- fp32 -> bf16 conversion (x and conv weights) -----------
__global__ __launch_bounds__(256) void cvt_bf16(const float* __restrict__ in,
                                                ushort* __restrict__ out, int n4) {
  int i = blockIdx.x * 256 + threadIdx.x;
  if (i >= n4) return;
  float4 v = ((const float4*)in)[i];
  ushort4 u;
  u.x = f2bf(v.x); u.y = f2bf(v.y); u.z = f2bf(v.z); u.w = f2bf(v.w);
  ((ushort4*)out)[i] = u;
}

// ---------------- degree count -------------------------------------------
__global__ __launch_bounds__(256) void count_deg(const int* __restrict__ dst,
                                                 int* __restrict__ cnt) {
  int e = blockIdx.x * 256 + threadIdx.x;
  if (e < N_EDGES) atomicAdd(&cnt[dst[e]], 1);
}

// ---------------- dinv = rsqrt(deg+1) ------------------------------------
__global__ __launch_bounds__(256) void compute_dinv(const int* __restrict__ cnt,
                                                    float* __restrict__ dinv) {
  int i = blockIdx.x * 256 + threadIdx.x;
  if (i < N_NODES) dinv[i] = rsqrtf((float)cnt[i] + 1.0f);
}

// ---------------- exclusive scan (3 kernels) -----------------------------
__global__ __launch_bounds__(256) void scan1(const int* __restrict__ cnt,
                                             int* __restrict__ ptr,
                                             int* __restrict__ bsums) {
  __shared__ int tmp[256];
  int i = blockIdx.x * 256 + threadIdx.x;
  int v = (i < N_NODES) ? cnt[i] : 0;
  tmp[threadIdx.x] = v;
  __syncthreads();
  for (int off = 1; off < 256; off <<= 1) {
    int t = (threadIdx.x >= off) ? tmp[threadIdx.x - off] : 0;
    __syncthreads();
    tmp[threadIdx.x] += t;
    __syncthreads();
  }
  if (i < N_NODES) ptr[i] = tmp[threadIdx.x] - v;           // exclusive
  if (threadIdx.x == 255) bsums[blockIdx.x] = tmp[255];
}

__global__ __launch_bounds__(256) void scan2(int* __restrict__ bsums, int nb) {
  __shared__ int tmp[256];
  int v = (threadIdx.x < nb) ? bsums[threadIdx.x] : 0;
  tmp[threadIdx.x] = v;
  __syncthreads();
  for (int off = 1; off < 256; off <<= 1) {
    int t = (threadIdx.x >= off) ? tmp[threadIdx.x - off] : 0;
    __syncthreads();
    tmp[threadIdx.x] += t;
    __syncthreads();
  }
  if (threadIdx.x < nb) bsums[threadIdx.x] = tmp[threadIdx.x] - v;  // exclusive
}

__global__ __launch_bounds__(256) void scan3(int* __restrict__ ptr,
                                             int* __restrict__ cursor,
                                             const int* __restrict__ bsums) {
  int i = blockIdx.x * 256 + threadIdx.x;
  if (i < N_NODES) {
    int p = ptr[i] + bsums[blockIdx.x];
    ptr[i] = p;
    cursor[i] = p;
  }
}

// ---------------- CSR fill (src + fused norm) ----------------------------
__global__ __launch_bounds__(256) void fill_csr(const int* __restrict__ src,
                                                const int* __restrict__ dst,
                                                const float* __restrict__ dinv,
                                                int* __restrict__ cursor,
                                                int2* __restrict__ edges) {
  int e = blockIdx.x * 256 + threadIdx.x;
  if (e >= N_EDGES) return;
  int s = src[e], d = dst[e];
  int pos = atomicAdd(&cursor[d], 1);
  float nrm = dinv[s] * dinv[d];
  edges[pos] = make_int2(s, __float_as_int(nrm));
}

// ---------------- GEMM [M,128] x [128,128] via MFMA bf16 -----------------
__global__ __launch_bounds__(256) void gemm128(const ushort* __restrict__ X,
                                               const ushort* __restrict__ W,
                                               float* __restrict__ XW,
                                               int nTilesM) {
  int wave = (blockIdx.x * 256 + threadIdx.x) >> 6;
  int lane = threadIdx.x & 63;
  int mt = wave >> 3;  // 8 n-tiles per m-tile
  int nt = wave & 7;
  if (mt >= nTilesM) return;
  int m0 = mt * 16, n0 = nt * 16;
  int r = lane & 15, quad = lane >> 4;
  floatx4 acc = {0.f, 0.f, 0.f, 0.f};
  const ushort* xrow = X + (size_t)(m0 + r) * FEAT;
#pragma unroll
  for (int kb = 0; kb < 4; ++kb) {
    int k0 = kb * 32 + quad * 8;
    short8 a = *(const short8*)(xrow + k0);
    short8 b;
#pragma unroll
    for (int j = 0; j < 8; ++j) b[j] = (short)W[(size_t)(k0 + j) * FEAT + n0 + r];
    acc = __builtin_amdgcn_mfma_f32_16x16x32_bf16(a, b, acc, 0, 0, 0);
  }
#pragma unroll
  for (int reg = 0; reg < 4; ++reg) {
    int row = quad * 4 + reg;
    XW[(size_t)(m0 + row) * FEAT + n0 + r] = acc[reg];
  }
}

// ---------------- aggregation: one wave per node -------------------------
__global__ __launch_bounds__(256) void agg_kernel(const float* __restrict__ XW,
                                                  const float* __restrict__ dinv,
                                                  const int* __restrict__ ptr,
                                                  const int* __restrict__ cnt,
                                                  const int2* __restrict__ edges,
                                                  const float* __restrict__ bias,
                                                  ushort* __restrict__ Hout,
                                                  float* __restrict__ f_sum,
                                                  const int* __restrict__ batch,
                                                  int mode) {
  int wave = (blockIdx.x * 256 + threadIdx.x) >> 6;
  int lane = threadIdx.x & 63;
  if (wave >= N_NODES) return;
  int v = wave;
  float di = dinv[v];
  const float2* xw2 = (const float2*)XW;   // 64 float2 per node row
  float2 self = xw2[(size_t)v * 64 + lane];
  float sn = di * di;
  float ax = self.x * sn, ay = self.y * sn;
  int start = ptr[v];
  int n = cnt[v];
  for (int i = 0; i < n; ++i) {
    int2 e = edges[start + i];
    float nrm = __int_as_float(e.y);
    float2 m = xw2[(size_t)e.x * 64 + lane];
    ax = fmaf(nrm, m.x, ax);
    ay = fmaf(nrm, m.y, ay);
  }
  ax += bias[2 * lane];
  ay += bias[2 * lane + 1];
  if (mode == 0) {
    ax = fmaxf(ax, 0.f);
    ay = fmaxf(ay, 0.f);
    ushort2 h2;
    h2.x = f2bf(ax);
    h2.y = f2bf(ay);
    ((ushort2*)Hout)[(size_t)v * 64 + lane] = h2;
  } else {
    int g = batch[v];
    atomicAdd(&f_sum[g * FEAT + 2 * lane], ax);
    atomicAdd(&f_sum[g * FEAT + 2 * lane + 1], ay);
  }
}

// ---------------- per-graph node counts (LDS binned) ---------------------
__global__ __launch_bounds__(256) void count_graphs(const int* __restrict__ batch,
                                                    float* __restrict__ cnt_g) {
  __shared__ int bins[NGRAPH];
  if (threadIdx.x < NGRAPH) bins[threadIdx.x] = 0;
  __syncthreads();
  int i = blockIdx.x * 256 + threadIdx.x;
  if (i < N_NODES) atomicAdd(&bins[batch[i]], 1);
  __syncthreads();
  if (threadIdx.x < NGRAPH && bins[threadIdx.x] > 0)
    atomicAdd(&cnt_g[threadIdx.x], (float)bins[threadIdx.x]);
}

// ---------------- finalize f = sums / cnt (fp32 out, is output 0) --------
__global__ __launch_bounds__(256) void finalize_f(const float* __restrict__ f_sum,
                                                  const float* __restrict__ cnt_g,
                                                  float* __restrict__ out_f) {
  int i = blockIdx.x * 256 + threadIdx.x;
  if (i < NGRAPH * FEAT) {
    float c = fmaxf(cnt_g[i >> 7], 1.0f);
    out_f[i] = f_sum[i] / c;
  }
}

// ---------------- FC head: split-K atomic GEMM ---------------------------
// fc_init: out[r][c] = b[c]
__global__ __launch_bounds__(256) void fc_init(const float* __restrict__ b,
                                               float* __restrict__ out, int C) {
  int i = blockIdx.x * 256 + threadIdx.x;
  if (i < NGRAPH * C) out[i] = b[i % C];
}

// fc_accum: one wave = (row r, 64-col strip, 64-deep K chunk).
// Applies relu to the INPUT when relu_in=1 (previous layer's activation).
// 4 independent accumulators for ILP; coalesced 256B w-loads per iter;
// one atomicAdd per output element.
__global__ __launch_bounds__(256) void fc_accum(const float* __restrict__ in,
                                                const float* __restrict__ w,
                                                float* __restrict__ out,
                                                int K, int C, int relu_in,
                                                int cstrips, int kchunks) {
  int wave = (blockIdx.x * 256 + threadIdx.x) >> 6;
  int lane = threadIdx.x & 63;
  int perrow = cstrips * kchunks;
  int r = wave / perrow;
  if (r >= NGRAPH) return;
  int rem = wave - r * perrow;
  int cs = rem / kchunks;
  int kc = rem - cs * kchunks;
  int c = cs * 64 + lane;
  if (c >= C) return;
  const float* inr = in + (size_t)r * K + kc * 64;
  const float* wp = w + (size_t)(kc * 64) * C + c;
  float a0 = 0.f, a1 = 0.f, a2 = 0.f, a3 = 0.f;
#pragma unroll 4
  for (int k = 0; k < 64; k += 4) {
    float i0 = inr[k], i1 = inr[k + 1], i2 = inr[k + 2], i3 = inr[k + 3];
    if (relu_in) {
      i0 = fmaxf(i0, 0.f); i1 = fmaxf(i1, 0.f);
      i2 = fmaxf(i2, 0.f); i3 = fmaxf(i3, 0.f);
    }
    a0 = fmaf(i0, wp[(size_t)k * C], a0);
    a1 = fmaf(i1, wp[(size_t)(k + 1) * C], a1);
    a2 = fmaf(i2, wp[(size_t)(k + 2) * C], a2);
    a3 = fmaf(i3, wp[(size_t)(k + 3) * C], a3);
  }
  atomicAdd(&out[(size_t)r * C + c], (a0 + a1) + (a2 + a3));
}

static inline void fc_run(const float* in, const float* w, const float* b,
                          float* out, int K, int C, int relu_in,
                          hipStream_t stream) {
  int cstrips = (C + 63) / 64;
  int kchunks = K / 64;
  fc_init<<<(NGRAPH * C + 255) / 256, 256, 0, stream>>>(b, out, C);
  int waves = NGRAPH * cstrips * kchunks;
  fc_accum<<<(waves * 64 + 255) / 256, 256, 0, stream>>>(in, w, out, K, C,
                                                         relu_in, cstrips, kchunks);
}

// =========================================================================
extern "C" void kernel_launch(void* const* d_in, const int* in_sizes, int n_in,
                              void* d_out, int out_size, void* d_ws, size_t ws_size,
                              hipStream_t stream) {
  const float* x         = (const float*)d_in[0];
  const int*   ei        = (const int*)d_in[1];     // [2][E]: row0 src, row1 dst
  const int*   batch     = (const int*)d_in[2];
  const float* conv_w[3] = {(const float*)d_in[3], (const float*)d_in[5], (const float*)d_in[7]};
  const float* conv_b[3] = {(const float*)d_in[4], (const float*)d_in[6], (const float*)d_in[8]};
  const float* fc_w[5]   = {(const float*)d_in[9],  (const float*)d_in[11],
                            (const float*)d_in[13], (const float*)d_in[15],
                            (const float*)d_in[17]};
  const float* fc_b[5]   = {(const float*)d_in[10], (const float*)d_in[12],
                            (const float*)d_in[14], (const float*)d_in[16],
                            (const float*)d_in[18]};
  const int* e_src = ei;
  const int* e_dst = ei + N_EDGES;
  float* out_f = (float*)d_out;                  // [64][128] fp32  (output 0)
  float* out_y = (float*)d_out + NGRAPH * FEAT;  // [64][10]  fp32  (output 1)

  char* p = (char*)d_ws;
  auto carve = [&](size_t bytes) {
    char* r = p;
    p += (bytes + 255) & ~(size_t)255;
    return r;
  };
  int*    cnt_i   = (int*)carve(N_NODES * 4);
  float*  dinv    = (float*)carve(N_NODES * 4);
  int*    csr_ptr = (int*)carve(N_NODES * 4);
  int*    cursor  = (int*)carve(N_NODES * 4);
  int*    bsums   = (int*)carve(256 * 4);
  int2*   edges   = (int2*)carve((size_t)N_EDGES * 8);
  ushort* xb      = (ushort*)carve((size_t)N_NODES * FEAT * 2);   // bf16 x
  ushort* wb      = (ushort*)carve((size_t)3 * FEAT * FEAT * 2);  // bf16 conv weights
  float*  xw      = (float*)carve((size_t)N_NODES * FEAT * 4);
  ushort* hbuf    = (ushort*)carve((size_t)N_NODES * FEAT * 2);
  float*  f_sum   = (float*)carve(NGRAPH * FEAT * 4);
  float*  cnt_g   = (float*)carve(NGRAPH * 4);
  float*  act1    = (float*)carve(NGRAPH * 1024 * 4);
  float*  act2    = (float*)carve(NGRAPH * 512 * 4);
  float*  act3    = (float*)carve(NGRAPH * 256 * 4);
  float*  act4    = (float*)carve(NGRAPH * 128 * 4);

  const int BLK_E = (N_EDGES + 255) / 256;   // 3125
  const int BLK_N = (N_NODES + 255) / 256;   // 196

  hipMemsetAsync(cnt_i, 0, N_NODES * 4, stream);
  hipMemsetAsync(f_sum, 0, NGRAPH * FEAT * 4, stream);
  hipMemsetAsync(cnt_g, 0, NGRAPH * 4, stream);

  // ---- fp32 -> bf16 prep (x, conv weights) ----
  cvt_bf16<<<(N_NODES * FEAT / 4 + 255) / 256, 256, 0, stream>>>(x, xb, N_NODES * FEAT / 4);
  cvt_bf16<<<(FEAT * FEAT / 4 + 255) / 256, 256, 0, stream>>>(conv_w[0], wb,                   FEAT * FEAT / 4);
  cvt_bf16<<<(FEAT * FEAT / 4 + 255) / 256, 256, 0, stream>>>(conv_w[1], wb + FEAT * FEAT,     FEAT * FEAT / 4);
  cvt_bf16<<<(FEAT * FEAT / 4 + 255) / 256, 256, 0, stream>>>(conv_w[2], wb + 2 * FEAT * FEAT, FEAT * FEAT / 4);

  // ---- build CSR + norms (once; reused by all 3 convs) ----
  count_deg<<<BLK_E, 256, 0, stream>>>(e_dst, cnt_i);
  compute_dinv<<<BLK_N, 256, 0, stream>>>(cnt_i, dinv);
  scan1<<<BLK_N, 256, 0, stream>>>(cnt_i, csr_ptr, bsums);
  scan2<<<1, 256, 0, stream>>>(bsums, BLK_N);
  scan3<<<BLK_N, 256, 0, stream>>>(csr_ptr, cursor, bsums);
  fill_csr<<<BLK_E, 256, 0, stream>>>(e_src, e_dst, dinv, cursor, edges);

  const int GEMM_BLKS = (N_NODES / 16) * 8 / 4;
  const int AGG_BLKS  = (N_NODES + 3) / 4;

  // ---- conv1 ----
  gemm128<<<GEMM_BLKS, 256, 0, stream>>>(xb, wb, xw, N_NODES / 16);
  agg_kernel<<<AGG_BLKS, 256, 0, stream>>>(xw, dinv, csr_ptr, cnt_i, edges,
                                           conv_b[0], hbuf, f_sum, batch, 0);
  // ---- conv2 ----
  gemm128<<<GEMM_BLKS, 256, 0, stream>>>(hbuf, wb + FEAT * FEAT, xw, N_NODES / 16);
  agg_kernel<<<AGG_BLKS, 256, 0, stream>>>(xw, dinv, csr_ptr, cnt_i, edges,
                                           conv_b[1], hbuf, f_sum, batch, 0);
  // ---- conv3 + fused mean-pool numerator ----
  gemm128<<<GEMM_BLKS, 256, 0, stream>>>(hbuf, wb + 2 * FEAT * FEAT, xw, N_NODES / 16);
  agg_kernel<<<AGG_BLKS, 256, 0, stream>>>(xw, dinv, csr_ptr, cnt_i, edges,
                                           conv_b[2], hbuf, f_sum, batch, 1);

  // ---- pool ----
  count_graphs<<<BLK_N, 256, 0, stream>>>(batch, cnt_g);
  finalize_f<<<(NGRAPH * FEAT + 255) / 256, 256, 0, stream>>>(f_sum, cnt_g, out_f);

  // ---- FC head: split-K atomic GEMMs, relu fused into next layer's read ----
  fc_run(out_f, fc_w[0], fc_b[0], act1, 128, 1024, 0, stream);  // fc1 (input f, no relu)
  fc_run(act1,  fc_w[1], fc_b[1], act2, 1024, 512, 1, stream);  // fc2 (relu fc1 out)
  fc_run(act2,  fc_w[2], fc_b[2], act3, 512, 256, 1, stream);   // fc3
  fc_run(act3,  fc_w[3], fc_b[3], act4, 256, 128, 1, stream);   // fc4
  fc_run(act4,  fc_w[4], fc_b[4], out_y, 128, 10, 1, stream);   // fc5 (no out relu)
}

// Round 4
// 639.514 us; speedup vs baseline: 1.7559x; 1.0972x over previous
//
#include <hip/hip_runtime.h>
#include <stdint.h>

#define N_NODES 50000
#define N_EDGES 800000
#define FEAT    128
#define NGRAPH  64

typedef __attribute__((ext_vector_type(8))) short short8;
typedef __attribute__((ext_vector_type(4))) float floatx4;

static __device__ __forceinline__ ushort f2bf(float f) {
  uint32_t x = __float_as_uint(f);
  x += 0x7FFF + ((x >> 16) & 1);   // RNE
  return (ushort)(x >> 16);
}

// ---------------- fp32 -> bf16 conversion (x and conv weights) -----------
__global__ __launch_bounds__(256) void cvt_bf16(const float* __restrict__ in,
                                                ushort* __restrict__ out, int n4) {
  int i = blockIdx.x * 256 + threadIdx.x;
  if (i >= n4) return;
  float4 v = ((const float4*)in)[i];
  ushort4 u;
  u.x = f2bf(v.x); u.y = f2bf(v.y); u.z = f2bf(v.z); u.w = f2bf(v.w);
  ((ushort4*)out)[i] = u;
}

// ---------------- degree count -------------------------------------------
__global__ __launch_bounds__(256) void count_deg(const int* __restrict__ dst,
                                                 int* __restrict__ cnt) {
  int e = blockIdx.x * 256 + threadIdx.x;
  if (e < N_EDGES) atomicAdd(&cnt[dst[e]], 1);
}

// ---------------- dinv = rsqrt(deg+1) ------------------------------------
__global__ __launch_bounds__(256) void compute_dinv(const int* __restrict__ cnt,
                                                    float* __restrict__ dinv) {
  int i = blockIdx.x * 256 + threadIdx.x;
  if (i < N_NODES) dinv[i] = rsqrtf((float)cnt[i] + 1.0f);
}

// ---------------- exclusive scan (3 kernels) -----------------------------
__global__ __launch_bounds__(256) void scan1(const int* __restrict__ cnt,
                                             int* __restrict__ ptr,
                                             int* __restrict__ bsums) {
  __shared__ int tmp[256];
  int i = blockIdx.x * 256 + threadIdx.x;
  int v = (i < N_NODES) ? cnt[i] : 0;
  tmp[threadIdx.x] = v;
  __syncthreads();
  for (int off = 1; off < 256; off <<= 1) {
    int t = (threadIdx.x >= off) ? tmp[threadIdx.x - off] : 0;
    __syncthreads();
    tmp[threadIdx.x] += t;
    __syncthreads();
  }
  if (i < N_NODES) ptr[i] = tmp[threadIdx.x] - v;           // exclusive
  if (threadIdx.x == 255) bsums[blockIdx.x] = tmp[255];
}

__global__ __launch_bounds__(256) void scan2(int* __restrict__ bsums, int nb) {
  __shared__ int tmp[256];
  int v = (threadIdx.x < nb) ? bsums[threadIdx.x] : 0;
  tmp[threadIdx.x] = v;
  __syncthreads();
  for (int off = 1; off < 256; off <<= 1) {
    int t = (threadIdx.x >= off) ? tmp[threadIdx.x - off] : 0;
    __syncthreads();
    tmp[threadIdx.x] += t;
    __syncthreads();
  }
  if (threadIdx.x < nb) bsums[threadIdx.x] = tmp[threadIdx.x] - v;  // exclusive
}

__global__ __launch_bounds__(256) void scan3(int* __restrict__ ptr,
                                             int* __restrict__ cursor,
                                             const int* __restrict__ bsums) {
  int i = blockIdx.x * 256 + threadIdx.x;
  if (i < N_NODES) {
    int p = ptr[i] + bsums[blockIdx.x];
    ptr[i] = p;
    cursor[i] = p;
  }
}

// ---------------- CSR fill (src + fused norm) ----------------------------
__global__ __launch_bounds__(256) void fill_csr(const int* __restrict__ src,
                                                const int* __restrict__ dst,
                                                const float* __restrict__ dinv,
                                                int* __restrict__ cursor,
                                                int2* __restrict__ edges) {
  int e = blockIdx.x * 256 + threadIdx.x;
  if (e >= N_EDGES) return;
  int s = src[e], d = dst[e];
  int pos = atomicAdd(&cursor[d], 1);
  float nrm = dinv[s] * dinv[d];
  edges[pos] = make_int2(s, __float_as_int(nrm));
}

// ---------------- GEMM [M,128] x [128,128] via MFMA bf16 -----------------
__global__ __launch_bounds__(256) void gemm128(const ushort* __restrict__ X,
                                               const ushort* __restrict__ W,
                                               float* __restrict__ XW,
                                               int nTilesM) {
  int wave = (blockIdx.x * 256 + threadIdx.x) >> 6;
  int lane = threadIdx.x & 63;
  int mt = wave >> 3;  // 8 n-tiles per m-tile
  int nt = wave & 7;
  if (mt >= nTilesM) return;
  int m0 = mt * 16, n0 = nt * 16;
  int r = lane & 15, quad = lane >> 4;
  floatx4 acc = {0.f, 0.f, 0.f, 0.f};
  const ushort* xrow = X + (size_t)(m0 + r) * FEAT;
#pragma unroll
  for (int kb = 0; kb < 4; ++kb) {
    int k0 = kb * 32 + quad * 8;
    short8 a = *(const short8*)(xrow + k0);
    short8 b;
#pragma unroll
    for (int j = 0; j < 8; ++j) b[j] = (short)W[(size_t)(k0 + j) * FEAT + n0 + r];
    acc = __builtin_amdgcn_mfma_f32_16x16x32_bf16(a, b, acc, 0, 0, 0);
  }
#pragma unroll
  for (int reg = 0; reg < 4; ++reg) {
    int row = quad * 4 + reg;
    XW[(size_t)(m0 + row) * FEAT + n0 + r] = acc[reg];
  }
}

// ---------------- aggregation: one wave per node, 8-deep gather ILP ------
// mode 0: h = relu(agg + b) -> bf16 Hout (next GEMM's A operand)
// mode 1: v = agg + b; atomicAdd into f_sum[batch[node]*128 + feat]
__global__ __launch_bounds__(256) void agg_kernel(const float* __restrict__ XW,
                                                  const float* __restrict__ dinv,
                                                  const int* __restrict__ ptr,
                                                  const int* __restrict__ cnt,
                                                  const int2* __restrict__ edges,
                                                  const float* __restrict__ bias,
                                                  ushort* __restrict__ Hout,
                                                  float* __restrict__ f_sum,
                                                  const int* __restrict__ batch,
                                                  int mode) {
  int wave = (blockIdx.x * 256 + threadIdx.x) >> 6;
  int lane = threadIdx.x & 63;
  if (wave >= N_NODES) return;
  int v = wave;
  float di = dinv[v];
  const float2* xw2 = (const float2*)XW;   // 64 float2 per node row
  float2 self = xw2[(size_t)v * 64 + lane];
  float sn = di * di;
  float ax0 = self.x * sn, ay0 = self.y * sn;
  float ax1 = 0.f, ay1 = 0.f, ax2 = 0.f, ay2 = 0.f, ax3 = 0.f, ay3 = 0.f;
  int start = ptr[v];
  int n = cnt[v];
  int i = 0;
  // peel one edge if start is odd so int4 edge loads are 16B-aligned
  if ((start & 1) && n > 0) {
    int2 e = edges[start];
    float2 m = xw2[(size_t)e.x * 64 + lane];
    float nrm = __int_as_float(e.y);
    ax0 = fmaf(nrm, m.x, ax0);
    ay0 = fmaf(nrm, m.y, ay0);
    i = 1;
  }
  // main loop: 8 edges per iteration, 8 independent gathers in flight
  for (; i + 8 <= n; i += 8) {
    const int4* ep = (const int4*)(edges + start + i);   // 16B-aligned
    int4 q0 = ep[0], q1 = ep[1], q2 = ep[2], q3 = ep[3];
    float2 m0 = xw2[(size_t)q0.x * 64 + lane];
    float2 m1 = xw2[(size_t)q0.z * 64 + lane];
    float2 m2 = xw2[(size_t)q1.x * 64 + lane];
    float2 m3 = xw2[(size_t)q1.z * 64 + lane];
    float2 m4 = xw2[(size_t)q2.x * 64 + lane];
    float2 m5 = xw2[(size_t)q2.z * 64 + lane];
    float2 m6 = xw2[(size_t)q3.x * 64 + lane];
    float2 m7 = xw2[(size_t)q3.z * 64 + lane];
    float n0 = __int_as_float(q0.y), n1 = __int_as_float(q0.w);
    float n2 = __int_as_float(q1.y), n3 = __int_as_float(q1.w);
    float n4 = __int_as_float(q2.y), n5 = __int_as_float(q2.w);
    float n6 = __int_as_float(q3.y), n7 = __int_as_float(q3.w);
    ax0 = fmaf(n0, m0.x, ax0); ay0 = fmaf(n0, m0.y, ay0);
    ax1 = fmaf(n1, m1.x, ax1); ay1 = fmaf(n1, m1.y, ay1);
    ax2 = fmaf(n2, m2.x, ax2); ay2 = fmaf(n2, m2.y, ay2);
    ax3 = fmaf(n3, m3.x, ax3); ay3 = fmaf(n3, m3.y, ay3);
    ax0 = fmaf(n4, m4.x, ax0); ay0 = fmaf(n4, m4.y, ay0);
    ax1 = fmaf(n5, m5.x, ax1); ay1 = fmaf(n5, m5.y, ay1);
    ax2 = fmaf(n6, m6.x, ax2); ay2 = fmaf(n6, m6.y, ay2);
    ax3 = fmaf(n7, m7.x, ax3); ay3 = fmaf(n7, m7.y, ay3);
  }
  // tail
  for (; i < n; ++i) {
    int2 e = edges[start + i];
    float nrm = __int_as_float(e.y);
    float2 m = xw2[(size_t)e.x * 64 + lane];
    ax0 = fmaf(nrm, m.x, ax0);
    ay0 = fmaf(nrm, m.y, ay0);
  }
  float ax = (ax0 + ax1) + (ax2 + ax3) + bias[2 * lane];
  float ay = (ay0 + ay1) + (ay2 + ay3) + bias[2 * lane + 1];
  if (mode == 0) {
    ax = fmaxf(ax, 0.f);
    ay = fmaxf(ay, 0.f);
    ushort2 h2;
    h2.x = f2bf(ax);
    h2.y = f2bf(ay);
    ((ushort2*)Hout)[(size_t)v * 64 + lane] = h2;
  } else {
    int g = batch[v];
    atomicAdd(&f_sum[g * FEAT + 2 * lane], ax);
    atomicAdd(&f_sum[g * FEAT + 2 * lane + 1], ay);
  }
}

// ---------------- per-graph node counts (LDS binned) ---------------------
__global__ __launch_bounds__(256) void count_graphs(const int* __restrict__ batch,
                                                    float* __restrict__ cnt_g) {
  __shared__ int bins[NGRAPH];
  if (threadIdx.x < NGRAPH) bins[threadIdx.x] = 0;
  __syncthreads();
  int i = blockIdx.x * 256 + threadIdx.x;
  if (i < N_NODES) atomicAdd(&bins[batch[i]], 1);
  __syncthreads();
  if (threadIdx.x < NGRAPH && bins[threadIdx.x] > 0)
    atomicAdd(&cnt_g[threadIdx.x], (float)bins[threadIdx.x]);
}

// ---------------- finalize f = sums / cnt (fp32 out, is output 0) --------
__global__ __launch_bounds__(256) void finalize_f(const float* __restrict__ f_sum,
                                                  const float* __restrict__ cnt_g,
                                                  float* __restrict__ out_f) {
  int i = blockIdx.x * 256 + threadIdx.x;
  if (i < NGRAPH * FEAT) {
    float c = fmaxf(cnt_g[i >> 7], 1.0f);
    out_f[i] = f_sum[i] / c;
  }
}

// ---------------- FC head: split-K atomic GEMM ---------------------------
__global__ __launch_bounds__(256) void fc_init(const float* __restrict__ b,
                                               float* __restrict__ out, int C) {
  int i = blockIdx.x * 256 + threadIdx.x;
  if (i < NGRAPH * C) out[i] = b[i % C];
}

__global__ __launch_bounds__(256) void fc_accum(const float* __restrict__ in,
                                                const float* __restrict__ w,
                                                float* __restrict__ out,
                                                int K, int C, int relu_in,
                                                int cstrips, int kchunks) {
  int wave = (blockIdx.x * 256 + threadIdx.x) >> 6;
  int lane = threadIdx.x & 63;
  int perrow = cstrips * kchunks;
  int r = wave / perrow;
  if (r >= NGRAPH) return;
  int rem = wave - r * perrow;
  int cs = rem / kchunks;
  int kc = rem - cs * kchunks;
  int c = cs * 64 + lane;
  if (c >= C) return;
  const float* inr = in + (size_t)r * K + kc * 64;
  const float* wp = w + (size_t)(kc * 64) * C + c;
  float a0 = 0.f, a1 = 0.f, a2 = 0.f, a3 = 0.f;
#pragma unroll 4
  for (int k = 0; k < 64; k += 4) {
    float i0 = inr[k], i1 = inr[k + 1], i2 = inr[k + 2], i3 = inr[k + 3];
    if (relu_in) {
      i0 = fmaxf(i0, 0.f); i1 = fmaxf(i1, 0.f);
      i2 = fmaxf(i2, 0.f); i3 = fmaxf(i3, 0.f);
    }
    a0 = fmaf(i0, wp[(size_t)k * C], a0);
    a1 = fmaf(i1, wp[(size_t)(k + 1) * C], a1);
    a2 = fmaf(i2, wp[(size_t)(k + 2) * C], a2);
    a3 = fmaf(i3, wp[(size_t)(k + 3) * C], a3);
  }
  atomicAdd(&out[(size_t)r * C + c], (a0 + a1) + (a2 + a3));
}

static inline void fc_run(const float* in, const float* w, const float* b,
                          float* out, int K, int C, int relu_in,
                          hipStream_t stream) {
  int cstrips = (C + 63) / 64;
  int kchunks = K / 64;
  fc_init<<<(NGRAPH * C + 255) / 256, 256, 0, stream>>>(b, out, C);
  int waves = NGRAPH * cstrips * kchunks;
  fc_accum<<<(waves * 64 + 255) / 256, 256, 0, stream>>>(in, w, out, K, C,
                                                         relu_in, cstrips, kchunks);
}

// =========================================================================
extern "C" void kernel_launch(void* const* d_in, const int* in_sizes, int n_in,
                              void* d_out, int out_size, void* d_ws, size_t ws_size,
                              hipStream_t stream) {
  const float* x         = (const float*)d_in[0];
  const int*   ei        = (const int*)d_in[1];     // [2][E]: row0 src, row1 dst
  const int*   batch     = (const int*)d_in[2];
  const float* conv_w[3] = {(const float*)d_in[3], (const float*)d_in[5], (const float*)d_in[7]};
  const float* conv_b[3] = {(const float*)d_in[4], (const float*)d_in[6], (const float*)d_in[8]};
  const float* fc_w[5]   = {(const float*)d_in[9],  (const float*)d_in[11],
                            (const float*)d_in[13], (const float*)d_in[15],
                            (const float*)d_in[17]};
  const float* fc_b[5]   = {(const float*)d_in[10], (const float*)d_in[12],
                            (const float*)d_in[14], (const float*)d_in[16],
                            (const float*)d_in[18]};
  const int* e_src = ei;
  const int* e_dst = ei + N_EDGES;
  float* out_f = (float*)d_out;                  // [64][128] fp32  (output 0)
  float* out_y = (float*)d_out + NGRAPH * FEAT;  // [64][10]  fp32  (output 1)

  char* p = (char*)d_ws;
  auto carve = [&](size_t bytes) {
    char* r = p;
    p += (bytes + 255) & ~(size_t)255;
    return r;
  };
  int*    cnt_i   = (int*)carve(N_NODES * 4);
  float*  dinv    = (float*)carve(N_NODES * 4);
  int*    csr_ptr = (int*)carve(N_NODES * 4);
  int*    cursor  = (int*)carve(N_NODES * 4);
  int*    bsums   = (int*)carve(256 * 4);
  int2*   edges   = (int2*)carve((size_t)N_EDGES * 8);
  ushort* xb      = (ushort*)carve((size_t)N_NODES * FEAT * 2);   // bf16 x
  ushort* wb      = (ushort*)carve((size_t)3 * FEAT * FEAT * 2);  // bf16 conv weights
  float*  xw      = (float*)carve((size_t)N_NODES * FEAT * 4);
  ushort* hbuf    = (ushort*)carve((size_t)N_NODES * FEAT * 2);
  float*  f_sum   = (float*)carve(NGRAPH * FEAT * 4);
  float*  cnt_g   = (float*)carve(NGRAPH * 4);
  float*  act1    = (float*)carve(NGRAPH * 1024 * 4);
  float*  act2    = (float*)carve(NGRAPH * 512 * 4);
  float*  act3    = (float*)carve(NGRAPH * 256 * 4);
  float*  act4    = (float*)carve(NGRAPH * 128 * 4);

  const int BLK_E = (N_EDGES + 255) / 256;   // 3125
  const int BLK_N = (N_NODES + 255) / 256;   // 196

  hipMemsetAsync(cnt_i, 0, N_NODES * 4, stream);
  hipMemsetAsync(f_sum, 0, NGRAPH * FEAT * 4, stream);
  hipMemsetAsync(cnt_g, 0, NGRAPH * 4, stream);

  // ---- fp32 -> bf16 prep (x, conv weights) ----
  cvt_bf16<<<(N_NODES * FEAT / 4 + 255) / 256, 256, 0, stream>>>(x, xb, N_NODES * FEAT / 4);
  cvt_bf16<<<(FEAT * FEAT / 4 + 255) / 256, 256, 0, stream>>>(conv_w[0], wb,                   FEAT * FEAT / 4);
  cvt_bf16<<<(FEAT * FEAT / 4 + 255) / 256, 256, 0, stream>>>(conv_w[1], wb + FEAT * FEAT,     FEAT * FEAT / 4);
  cvt_bf16<<<(FEAT * FEAT / 4 + 255) / 256, 256, 0, stream>>>(conv_w[2], wb + 2 * FEAT * FEAT, FEAT * FEAT / 4);

  // ---- build CSR + norms (once; reused by all 3 convs) ----
  count_deg<<<BLK_E, 256, 0, stream>>>(e_dst, cnt_i);
  compute_dinv<<<BLK_N, 256, 0, stream>>>(cnt_i, dinv);
  scan1<<<BLK_N, 256, 0, stream>>>(cnt_i, csr_ptr, bsums);
  scan2<<<1, 256, 0, stream>>>(bsums, BLK_N);
  scan3<<<BLK_N, 256, 0, stream>>>(csr_ptr, cursor, bsums);
  fill_csr<<<BLK_E, 256, 0, stream>>>(e_src, e_dst, dinv, cursor, edges);

  const int GEMM_BLKS = (N_NODES / 16) * 8 / 4;
  const int AGG_BLKS  = (N_NODES + 3) / 4;

  // ---- conv1 ----
  gemm128<<<GEMM_BLKS, 256, 0, stream>>>(xb, wb, xw, N_NODES / 16);
  agg_kernel<<<AGG_BLKS, 256, 0, stream>>>(xw, dinv, csr_ptr, cnt_i, edges,
                                           conv_b[0], hbuf, f_sum, batch, 0);
  // ---- conv2 ----
  gemm128<<<GEMM_BLKS, 256, 0, stream>>>(hbuf, wb + FEAT * FEAT, xw, N_NODES / 16);
  agg_kernel<<<AGG_BLKS, 256, 0, stream>>>(xw, dinv, csr_ptr, cnt_i, edges,
                                           conv_b[1], hbuf, f_sum, batch, 0);
  // ---- conv3 + fused mean-pool numerator ----
  gemm128<<<GEMM_BLKS, 256, 0, stream>>>(hbuf, wb + 2 * FEAT * FEAT, xw, N_NODES / 16);
  agg_kernel<<<AGG_BLKS, 256, 0, stream>>>(xw, dinv, csr_ptr, cnt_i, edges,
                                           conv_b[2], hbuf, f_sum, batch, 1);

  // ---- pool ----
  count_graphs<<<BLK_N, 256, 0, stream>>>(batch, cnt_g);
  finalize_f<<<(NGRAPH * FEAT + 255) / 256, 256, 0, stream>>>(f_sum, cnt_g, out_f);

  // ---- FC head: split-K atomic GEMMs, relu fused into next layer's read ----
  fc_run(out_f, fc_w[0], fc_b[0], act1, 128, 1024, 0, stream);  // fc1
  fc_run(act1,  fc_w[1], fc_b[1], act2, 1024, 512, 1, stream);  // fc2
  fc_run(act2,  fc_w[2], fc_b[2], act3, 512, 256, 1, stream);   // fc3
  fc_run(act3,  fc_w[3], fc_b[3], act4, 256, 128, 1, stream);   // fc4
  fc_run(act4,  fc_w[4], fc_b[4], out_y, 128, 10, 1, stream);   // fc5
}